// Round 8
// baseline (156.908 us; speedup 1.0000x reference)
//
#include <hip/hip_runtime.h>
#include <hip/hip_bf16.h>

// CrossAttention: B=4, C=256, H=W=64 -> N=M=4096, RC=32
// v8: split-m removed. attn: grid 256 x 512thr (8 waves, 2/SIMD, 1 block/CU),
//     full M per block, fused gamma*O/l + x epilogue (combine deleted).
//     Wave w: S^T u-pair (w&1) of tile (w>>1); PV for all 4 tiles over
//     d-tiles {2w,2w+1}. prep/fused_proj unchanged from v7.

#define B_ 4
#define C_ 256
#define N_ 4096
#define M_ 4096
#define SCALE_ 0.17677669529663687f  // 1/sqrt(32)

typedef __bf16 bf16x8 __attribute__((ext_vector_type(8)));
typedef float f32x4 __attribute__((ext_vector_type(4)));

#define AS1 __attribute__((address_space(1)))
#define AS3 __attribute__((address_space(3)))

static __device__ __forceinline__ unsigned short f2bf(float f) {
    unsigned int u = __float_as_uint(f);
    return (unsigned short)((u + 0x7fffu + ((u >> 16) & 1u)) >> 16);
}
static __device__ __forceinline__ unsigned bfpk(float a, float b) {
    return (unsigned)f2bf(a) | ((unsigned)f2bf(b) << 16);
}
static __device__ __forceinline__ void gload_lds16(const void* g, void* l) {
    __builtin_amdgcn_global_load_lds((const AS1 unsigned int*)g,
                                     (AS3 unsigned int*)l, 16, 0, 0);
}

// ---------------------------------------------------------------------------
// prep: weights -> bf16 MFMA fragment order. grid 40 x 256.
// ---------------------------------------------------------------------------
__global__ __launch_bounds__(256) void prep(
        const float* __restrict__ Wq, const float* __restrict__ Wk,
        const float* __restrict__ Wv, uint4* __restrict__ Wqf,
        uint4* __restrict__ Wkf, uint4* __restrict__ Wvf) {
    int bid = blockIdx.x, t = threadIdx.x;
    const float* W;
    uint4* dst;
    int frag;
    if (bid < 32)      { W = Wv; dst = Wvf; frag = (bid * 256 + t) >> 6; }
    else if (bid < 36) { W = Wq; dst = Wqf; frag = ((bid - 32) * 256 + t) >> 6; }
    else               { W = Wk; dst = Wkf; frag = ((bid - 36) * 256 + t) >> 6; }
    int lane = t & 63, low = lane & 15, q = lane >> 4;
    int fch = frag & 7, fr = frag >> 3;
    const float* wp = W + (size_t)(fr * 16 + low) * C_ + fch * 32 + q * 8;
    float4 w0 = *(const float4*)wp;
    float4 w1 = *(const float4*)(wp + 4);
    uint4 pk = {bfpk(w0.x, w0.y), bfpk(w0.z, w0.w),
                bfpk(w1.x, w1.y), bfpk(w1.z, w1.w)};
    dst[(size_t)frag * 64 + lane] = pk;
}

// ---------------------------------------------------------------------------
// Fused transpose + projections. grid 512 x 256. (unchanged from v7)
// ---------------------------------------------------------------------------
__global__ __launch_bounds__(256, 2) void fused_proj(
        const float* __restrict__ x, const float* __restrict__ ctx,
        const uint4* __restrict__ Wqf, const uint4* __restrict__ Wkf,
        const uint4* __restrict__ Wvf,
        const float* __restrict__ bq, const float* __restrict__ bk,
        const float* __restrict__ bv,
        unsigned short* __restrict__ Qf, unsigned short* __restrict__ Kf,
        unsigned char* __restrict__ Vf) {
    __shared__ unsigned short X[64][264];
    __shared__ unsigned short Pl[4][16 * 40];
    __shared__ unsigned char  Vw[4][16 * 40];

    int bid = blockIdx.x;
    bool isX = bid >= 256;
    int lb = bid & 255;
    int b = lb >> 6, pt64 = lb & 63;
    const float* __restrict__ in = (isX ? x : ctx) + (size_t)b * C_ * N_ + pt64 * 64;
    int t = threadIdx.x, wg = t >> 6, lane = t & 63;
    int low = lane & 15, q = lane >> 4;

    {
        int pL = lane;
        const float* s0 = in + pL;
#pragma unroll
        for (int ct = 0; ct < 4; ct++) {
            const float* s2 = s0 + (size_t)(ct * 64 + wg * 16) * N_;
            float v[16];
#pragma unroll
            for (int k = 0; k < 16; k++) v[k] = s2[(size_t)k * N_];
#pragma unroll
            for (int k = 0; k < 16; k += 2)
                *(unsigned*)&X[pL][ct * 64 + wg * 16 + k] = bfpk(v[k], v[k + 1]);
        }
    }
    __syncthreads();

    {
        const uint4* __restrict__ Wf = isX ? Wqf : Wkf;
        const float* __restrict__ bias = isX ? bq : bk;
        unsigned short* __restrict__ dst = isX ? Qf : Kf;
        bf16x8 xf[8];
#pragma unroll
        for (int ch = 0; ch < 8; ch++)
            xf[ch] = *(const bf16x8*)&X[wg * 16 + low][ch * 32 + q * 8];
        const f32x4 zero = {0.f, 0.f, 0.f, 0.f};
        f32x4 acc[2] = {zero, zero};
#pragma unroll
        for (int rt = 0; rt < 2; rt++)
#pragma unroll
            for (int ch = 0; ch < 8; ch++) {
                uint4 wv = Wf[(rt * 8 + ch) * 64 + lane];
                acc[rt] = __builtin_amdgcn_mfma_f32_16x16x32_bf16(
                    __builtin_bit_cast(bf16x8, wv), xf[ch], acc[rt], 0, 0, 0);
            }
        unsigned short* Pw = &Pl[wg][0];
#pragma unroll
        for (int rt = 0; rt < 2; rt++) {
            float b0 = bias[rt * 16 + q * 4 + 0], b1 = bias[rt * 16 + q * 4 + 1];
            float b2 = bias[rt * 16 + q * 4 + 2], b3 = bias[rt * 16 + q * 4 + 3];
            uint2 pk = {bfpk(acc[rt][0] + b0, acc[rt][1] + b1),
                        bfpk(acc[rt][2] + b2, acc[rt][3] + b3)};
            *(uint2*)(Pw + low * 40 + rt * 16 + q * 4) = pk;
        }
        uint4 frag = *(const uint4*)(Pw + low * 40 + q * 8);
        ((uint4*)dst)[((size_t)b * 256 + pt64 * 4 + wg) * 64 + lane] = frag;
    }

    if (!isX) {
        int mstep = wg >> 1, dh = wg & 1;
        bf16x8 vfr[2][8];
#pragma unroll
        for (int mt = 0; mt < 2; mt++)
#pragma unroll
            for (int ch = 0; ch < 8; ch++)
                vfr[mt][ch] = *(const bf16x8*)&X[mstep * 32 + mt * 16 + low][ch * 32 + q * 8];
        unsigned char* Vv = &Vw[wg][0];
        int msg = pt64 * 2 + mstep;
        const f32x4 zero = {0.f, 0.f, 0.f, 0.f};
#pragma unroll
        for (int dt8 = 0; dt8 < 8; dt8++) {
            int dt = dh * 8 + dt8;
            f32x4 a0 = zero, a1 = zero;
#pragma unroll
            for (int ch = 0; ch < 8; ch++) {
                uint4 wv = Wvf[(dt * 8 + ch) * 64 + lane];
                bf16x8 wfr = __builtin_bit_cast(bf16x8, wv);
                a0 = __builtin_amdgcn_mfma_f32_16x16x32_bf16(vfr[0][ch], wfr, a0, 0, 0, 0);
                a1 = __builtin_amdgcn_mfma_f32_16x16x32_bf16(vfr[1][ch], wfr, a1, 0, 0, 0);
            }
            float bb = bv[dt * 16 + low];
            unsigned w0 = __builtin_amdgcn_cvt_pk_fp8_f32(a0[0] + bb, a0[1] + bb, 0, false);
            w0 = __builtin_amdgcn_cvt_pk_fp8_f32(a0[2] + bb, a0[3] + bb, w0, true);
            unsigned w1 = __builtin_amdgcn_cvt_pk_fp8_f32(a1[0] + bb, a1[1] + bb, 0, false);
            w1 = __builtin_amdgcn_cvt_pk_fp8_f32(a1[2] + bb, a1[3] + bb, w1, true);
            *(unsigned*)(Vv + low * 40 + q * 4) = w0;
            *(unsigned*)(Vv + low * 40 + 16 + q * 4) = w1;
            uint2 fr = *(const uint2*)(Vv + low * 40 + q * 8);
            ((uint2*)Vf)[(((size_t)b * 128 + msg) * 16 + dt) * 64 + lane] = fr;
        }
    }
}

// ---------------------------------------------------------------------------
// Flash attention v8, full-M, fused epilogue. grid 256 (1/CU), 512 thr.
// bid = b(2)|ng(6). Block: 4 q-tiles (64 n), all 64 V slabs (M=4096).
// Wave w (0..7): S^T for tile w>>1, u-pair w&1; PV for all tiles, d-tiles
// {2w,2w+1}. P fp8 [n][m] ping-pong in LDS; V 16KB slabs DMA double-buffered.
// Epilogue: out = gamma*O/l + x with C-layout dword stores (64B segments).
// ---------------------------------------------------------------------------
__global__ __launch_bounds__(512, 2) void attn(
        const unsigned short* __restrict__ Qf, const unsigned short* __restrict__ Kf,
        const unsigned char* __restrict__ Vf, const float* __restrict__ x,
        const float* __restrict__ gamma, float* __restrict__ out) {
    __shared__ __align__(16) unsigned char vbuf[2][16384];    // 32 KB
    __shared__ __align__(16) unsigned char Pb[2][4][16 * 72]; // 9216 B
    __shared__ float Lh[2][64];

    int bid = blockIdx.x;
    int b = bid >> 6, ng = bid & 63;
    int w = threadIdx.x >> 6, lane = threadIdx.x & 63;
    int q = lane >> 4, low = lane & 15;
    int tt_own = w >> 1, uh = w & 1;       // S-tile, u-pair
    int nt = ng * 4 + tt_own;

    const uint4* Qp = (const uint4*)Qf;
    const uint4* Kp = (const uint4*)Kf + (size_t)b * 256 * 64;
    const unsigned char* Vp = Vf + (size_t)b * 1048576;

    bf16x8 qa = __builtin_bit_cast(bf16x8, Qp[(size_t)(b * 256 + nt) * 64 + lane]);

    f32x4 acc[4][2];                        // [n-tile][d-tile-local]: O^T
#pragma unroll
    for (int tt = 0; tt < 4; tt++)
#pragma unroll
        for (int dd = 0; dd < 2; dd++) acc[tt][dd] = (f32x4){0.f, 0.f, 0.f, 0.f};
    float lacc = 0.f;
    const f32x4 zero = {0.f, 0.f, 0.f, 0.f};

    // ---- prologue: K(0), S^T(0), DMA V(0), K(1), P(0) ----
    uint4 kv[2];
#pragma unroll
    for (int uu = 0; uu < 2; uu++)
        kv[uu] = Kp[(size_t)(uh * 2 + uu) * 64 + lane];
    f32x4 s[2];
#pragma unroll
    for (int uu = 0; uu < 2; uu++)
        s[uu] = __builtin_amdgcn_mfma_f32_16x16x32_bf16(
            __builtin_bit_cast(bf16x8, kv[uu]), qa, zero, 0, 0, 0);
#pragma unroll
    for (int ii = 0; ii < 2; ii++) {
        int ck = w * 2 + ii;
        gload_lds16(Vp + ck * 1024 + lane * 16, &vbuf[0][0] + ck * 1024 + lane * 16);
    }
#pragma unroll
    for (int uu = 0; uu < 2; uu++)
        kv[uu] = Kp[(size_t)(4 + uh * 2 + uu) * 64 + lane];
    {
        unsigned char* Pw = &Pb[0][tt_own][0];
#pragma unroll
        for (int uu = 0; uu < 2; uu++) {
            float p0 = __expf(s[uu][0] * SCALE_), p1 = __expf(s[uu][1] * SCALE_);
            float p2 = __expf(s[uu][2] * SCALE_), p3 = __expf(s[uu][3] * SCALE_);
            lacc += p0 + p1 + p2 + p3;
            unsigned pw = __builtin_amdgcn_cvt_pk_fp8_f32(p0, p1, 0, false);
            pw = __builtin_amdgcn_cvt_pk_fp8_f32(p2, p3, pw, true);
            *(unsigned*)(Pw + low * 72 + (uh * 2 + uu) * 16 + q * 4) = pw;
        }
    }
    __syncthreads();

    // ---- main loop over 64 V slabs ----
    for (int i = 0; i < 64; i++) {
        int cur = i & 1, nxt = cur ^ 1;
        if (i < 63) {
            // DMA V(i+1)
#pragma unroll
            for (int ii = 0; ii < 2; ii++) {
                int ck = w * 2 + ii;
                gload_lds16(Vp + (size_t)(i + 1) * 16384 + ck * 1024 + lane * 16,
                            &vbuf[nxt][0] + ck * 1024 + lane * 16);
            }
            // S^T(i+1)
#pragma unroll
            for (int uu = 0; uu < 2; uu++)
                s[uu] = __builtin_amdgcn_mfma_f32_16x16x32_bf16(
                    __builtin_bit_cast(bf16x8, kv[uu]), qa, zero, 0, 0, 0);
            if (i < 62) {
#pragma unroll
                for (int uu = 0; uu < 2; uu++)
                    kv[uu] = Kp[(size_t)((i + 2) * 4 + uh * 2 + uu) * 64 + lane];
            }
        }

        // ---- PV(i): acc[tt][dd] += V^T P^T (16 MFMAs) ----
        const unsigned char* vb = &vbuf[cur][0];
        const unsigned char* Pr = &Pb[cur][0][0];
        long vfr[2][2];
#pragma unroll
        for (int dd = 0; dd < 2; dd++) {
            int dt = w * 2 + dd;
            vfr[dd][0] = *(const long*)(vb + dt * 512 + lane * 8);
            vfr[dd][1] = *(const long*)(vb + 8192 + dt * 512 + lane * 8);
        }
#pragma unroll
        for (int tt = 0; tt < 4; tt++) {
            long pf0 = *(const long*)(Pr + tt * 1152 + low * 72 + q * 8);
            long pf1 = *(const long*)(Pr + tt * 1152 + low * 72 + 32 + q * 8);
#pragma unroll
            for (int dd = 0; dd < 2; dd++) {
                acc[tt][dd] = __builtin_amdgcn_mfma_f32_16x16x32_fp8_fp8(
                    vfr[dd][0], pf0, acc[tt][dd], 0, 0, 0);
                acc[tt][dd] = __builtin_amdgcn_mfma_f32_16x16x32_fp8_fp8(
                    vfr[dd][1], pf1, acc[tt][dd], 0, 0, 0);
            }
        }

        // ---- exp/P(i+1) ----
        if (i < 63) {
            unsigned char* Pw = &Pb[nxt][tt_own][0];
#pragma unroll
            for (int uu = 0; uu < 2; uu++) {
                float p0 = __expf(s[uu][0] * SCALE_), p1 = __expf(s[uu][1] * SCALE_);
                float p2 = __expf(s[uu][2] * SCALE_), p3 = __expf(s[uu][3] * SCALE_);
                lacc += p0 + p1 + p2 + p3;
                unsigned pw = __builtin_amdgcn_cvt_pk_fp8_f32(p0, p1, 0, false);
                pw = __builtin_amdgcn_cvt_pk_fp8_f32(p2, p3, pw, true);
                *(unsigned*)(Pw + low * 72 + (uh * 2 + uu) * 16 + q * 4) = pw;
            }
        }
        __syncthreads();
    }

    // ---- l: quad-reduce, per-tile halves to LDS ----
    lacc += __shfl_xor(lacc, 16, 64);
    lacc += __shfl_xor(lacc, 32, 64);
    if (lane < 16) Lh[uh][tt_own * 16 + lane] = lacc;
    __syncthreads();

    // ---- epilogue: out = gamma*O/l + x (C-layout dword stores) ----
    float g = gamma[0];
#pragma unroll
    for (int tt = 0; tt < 4; tt++) {
        float l = Lh[0][tt * 16 + low] + Lh[1][tt * 16 + low];
        float sc = g / l;
#pragma unroll
        for (int dd = 0; dd < 2; dd++) {
            int d = (w * 2 + dd) * 16 + q * 4;
            size_t base = ((size_t)(b * 256 + d)) * (size_t)N_ + ng * 64 + tt * 16 + low;
#pragma unroll
            for (int r = 0; r < 4; r++)
                out[base + (size_t)r * N_] = acc[tt][dd][r] * sc + x[base + (size_t)r * N_];
        }
    }
}

// ---------------------------------------------------------------------------
extern "C" void kernel_launch(void* const* d_in, const int* in_sizes, int n_in,
                              void* d_out, int out_size, void* d_ws, size_t ws_size,
                              hipStream_t stream) {
    const float* x     = (const float*)d_in[0];
    const float* ctx   = (const float*)d_in[1];
    const float* Wq    = (const float*)d_in[2];
    const float* bq    = (const float*)d_in[3];
    const float* Wk    = (const float*)d_in[4];
    const float* bk    = (const float*)d_in[5];
    const float* Wv    = (const float*)d_in[6];
    const float* bv    = (const float*)d_in[7];
    const float* gamma = (const float*)d_in[8];
    float* out = (float*)d_out;

    // ws: Qf 1M | Kf 1M | Vf 4.2M | Wqf/Wkf 16K each | Wvf 128K
    unsigned short* Qf = (unsigned short*)d_ws;
    unsigned short* Kf = Qf + (size_t)B_ * N_ * 32;
    unsigned char*  Vf = (unsigned char*)(Kf + (size_t)B_ * M_ * 32);
    uint4* Wqf = (uint4*)(Vf + (size_t)B_ * M_ * C_);
    uint4* Wkf = Wqf + 16 * 64;
    uint4* Wvf = Wkf + 16 * 64;

    prep<<<40, 256, 0, stream>>>(Wq, Wk, Wv, Wqf, Wkf, Wvf);
    fused_proj<<<512, 256, 0, stream>>>(x, ctx, Wqf, Wkf, Wvf, bq, bk, bv, Qf, Kf, Vf);
    attn<<<256, 512, 0, stream>>>(Qf, Kf, Vf, x, gamma, out);
}